// Round 1
// baseline (1153.213 us; speedup 1.0000x reference)
//
#include <hip/hip_runtime.h>
#include <math.h>

#define BB 1024
#define TT 512
#define HID 32

__device__ __forceinline__ float sigmoidf_(float x){
    return 1.0f / (1.0f + __expf(-x));
}
__device__ __forceinline__ float tanhf_(float x){
    // stable: t=e^{2x}; tanh = 1 - 2/(t+1). t=inf -> 1; t=0 -> -1.
    float t = __expf(2.0f * x);
    return 1.0f - 2.0f / (t + 1.0f);
}

// Layer 0 bidirectional GRU. Block = 192 threads = one batch element, both dirs.
// Thread g in [0,96) of dir d computes gate-row g each step.
__global__ __launch_bounds__(192) void gru_l0(
    const float* __restrict__ x,      // (B,T,4)
    const float* __restrict__ w_ih,   // (2,96,4)
    const float* __restrict__ w_hh,   // (2,96,32)
    const float* __restrict__ b_ih,   // (2,96)
    const float* __restrict__ b_hh,   // (2,96)
    float* __restrict__ h1)           // (B,T,64)  [0:32]=fwd, [32:64]=bwd
{
    const int b    = blockIdx.x;
    const int tid  = threadIdx.x;
    const int d    = tid / 96;
    const int g    = tid % 96;
    const int i    = g & 31;
    const int gate = g >> 5;   // 0=r,1=z,2=n

    float wi[4];
    #pragma unroll
    for (int k = 0; k < 4; ++k) wi[k] = w_ih[(d*96 + g)*4 + k];
    float wh[32];
    #pragma unroll
    for (int j = 0; j < 32; ++j) wh[j] = w_hh[(d*96 + g)*32 + j];
    const float bi = b_ih[d*96 + g];
    const float bh = b_hh[d*96 + g];

    __shared__ __align__(16) float h_sh[2][32];
    __shared__ float s_zc[2][32];
    __shared__ float s_xn[2][32];
    __shared__ float s_hn[2][32];

    if (g < 32) h_sh[d][i] = 0.0f;
    float h_reg = 0.0f;
    __syncthreads();

    for (int t = 0; t < TT; ++t) {
        const int tx = d ? (TT - 1 - t) : t;
        const float4 xv = *reinterpret_cast<const float4*>(x + ((size_t)b*TT + tx)*4);
        float xg = bi + xv.x*wi[0] + xv.y*wi[1] + xv.z*wi[2] + xv.w*wi[3];
        float hg = bh;
        #pragma unroll
        for (int j4 = 0; j4 < 8; ++j4) {
            const float4 hv = *reinterpret_cast<const float4*>(&h_sh[d][j4*4]);
            hg += hv.x*wh[j4*4+0] + hv.y*wh[j4*4+1] + hv.z*wh[j4*4+2] + hv.w*wh[j4*4+3];
        }
        if (gate == 1) { s_zc[d][i] = xg + hg; }
        else if (gate == 2) { s_xn[d][i] = xg; s_hn[d][i] = hg; }
        const float rsum = xg + hg;   // valid for gate==0
        __syncthreads();
        if (gate == 0) {
            const float r = sigmoidf_(rsum);
            const float z = sigmoidf_(s_zc[d][i]);
            const float n = tanhf_(s_xn[d][i] + r * s_hn[d][i]);
            const float hnew = (1.0f - z)*n + z*h_reg;
            h_reg = hnew;
            h_sh[d][i] = hnew;
            h1[((size_t)b*TT + tx)*64 + d*32 + i] = hnew;
        }
        __syncthreads();
    }
}

// Layer 1 bidirectional GRU, input width 64, projection fused,
// input rows double-buffered in LDS.
__global__ __launch_bounds__(192) void gru_l1(
    const float* __restrict__ h1,     // (B,T,64)
    const float* __restrict__ w_ih,   // (2,96,64)
    const float* __restrict__ w_hh,   // (2,96,32)
    const float* __restrict__ b_ih,   // (2,96)
    const float* __restrict__ b_hh,   // (2,96)
    float* __restrict__ out2)         // (B,T,64)
{
    const int b    = blockIdx.x;
    const int tid  = threadIdx.x;
    const int d    = tid / 96;
    const int g    = tid % 96;
    const int i    = g & 31;
    const int gate = g >> 5;

    float4 wi[16];
    #pragma unroll
    for (int k4 = 0; k4 < 16; ++k4)
        wi[k4] = *reinterpret_cast<const float4*>(w_ih + ((size_t)(d*96 + g))*64 + k4*4);
    float wh[32];
    #pragma unroll
    for (int j = 0; j < 32; ++j) wh[j] = w_hh[(d*96 + g)*32 + j];
    const float bi = b_ih[d*96 + g];
    const float bh = b_hh[d*96 + g];

    __shared__ __align__(16) float h_sh[2][32];
    __shared__ __align__(16) float in_sh[2][2][64];  // [buf][dir][64]
    __shared__ float s_zc[2][32];
    __shared__ float s_xn[2][32];
    __shared__ float s_hn[2][32];

    if (g < 32) h_sh[d][i] = 0.0f;
    float h_reg = 0.0f;

    // loader role: tid<64 stages dir0 row; tid in [96,160) stages dir1 row
    int lane_ld = -1, d_ld = 0;
    if (tid < 64)                      { lane_ld = tid;      d_ld = 0; }
    else if (tid >= 96 && tid < 160)   { lane_ld = tid - 96; d_ld = 1; }
    if (lane_ld >= 0) {
        const int row = d_ld ? (TT - 1) : 0;
        in_sh[0][d_ld][lane_ld] = h1[((size_t)b*TT + row)*64 + lane_ld];
    }
    __syncthreads();

    int buf = 0;
    for (int t = 0; t < TT; ++t) {
        float xg = bi;
        #pragma unroll
        for (int k4 = 0; k4 < 16; ++k4) {
            const float4 hv = *reinterpret_cast<const float4*>(&in_sh[buf][d][k4*4]);
            xg += hv.x*wi[k4].x + hv.y*wi[k4].y + hv.z*wi[k4].z + hv.w*wi[k4].w;
        }
        float hg = bh;
        #pragma unroll
        for (int j4 = 0; j4 < 8; ++j4) {
            const float4 hv = *reinterpret_cast<const float4*>(&h_sh[d][j4*4]);
            hg += hv.x*wh[j4*4+0] + hv.y*wh[j4*4+1] + hv.z*wh[j4*4+2] + hv.w*wh[j4*4+3];
        }
        if (gate == 1) { s_zc[d][i] = xg + hg; }
        else if (gate == 2) { s_xn[d][i] = xg; s_hn[d][i] = hg; }
        const float rsum = xg + hg;

        // prefetch next input row into a register (global load issued early)
        float nx = 0.0f;
        if (lane_ld >= 0 && t + 1 < TT) {
            const int row = d_ld ? (TT - 2 - t) : (t + 1);
            nx = h1[((size_t)b*TT + row)*64 + lane_ld];
        }
        __syncthreads();
        if (lane_ld >= 0 && t + 1 < TT) in_sh[buf ^ 1][d_ld][lane_ld] = nx;

        if (gate == 0) {
            const float r = sigmoidf_(rsum);
            const float z = sigmoidf_(s_zc[d][i]);
            const float n = tanhf_(s_xn[d][i] + r * s_hn[d][i]);
            const float hnew = (1.0f - z)*n + z*h_reg;
            h_reg = hnew;
            h_sh[d][i] = hnew;
            const int tx = d ? (TT - 1 - t) : t;
            out2[((size_t)b*TT + tx)*64 + d*32 + i] = hnew;
        }
        __syncthreads();
        buf ^= 1;
    }
}

// Attention pooling + FC + sigmoid. One block per batch element.
__global__ __launch_bounds__(256) void attn_fc(
    const float* __restrict__ out2,   // (B,T,64)
    const float* __restrict__ attn_w, // (64)
    const float* __restrict__ attn_b, // (1)
    const float* __restrict__ fc_w,   // (64)
    const float* __restrict__ fc_b,   // (1)
    float* __restrict__ out)          // (B,1)
{
    const int b    = blockIdx.x;
    const int tid  = threadIdx.x;
    const int wave = tid >> 6;
    const int lane = tid & 63;

    __shared__ float logit_sh[TT];
    __shared__ float red_sh[4];
    __shared__ float ctx_sh[4][64];

    const float aw = attn_w[lane];
    const float ab = attn_b[0];

    // phase 1: logits[t] = out2[b,t,:]·attn_w + ab
    for (int t = wave; t < TT; t += 4) {
        float v = out2[((size_t)b*TT + t)*64 + lane] * aw;
        #pragma unroll
        for (int off = 32; off > 0; off >>= 1) v += __shfl_xor(v, off, 64);
        if (lane == 0) logit_sh[t] = v + ab;
    }
    __syncthreads();

    // phase 2: softmax over T
    float m = -INFINITY;
    for (int t = tid; t < TT; t += 256) m = fmaxf(m, logit_sh[t]);
    #pragma unroll
    for (int off = 32; off > 0; off >>= 1) m = fmaxf(m, __shfl_xor(m, off, 64));
    if (lane == 0) red_sh[wave] = m;
    __syncthreads();
    m = fmaxf(fmaxf(red_sh[0], red_sh[1]), fmaxf(red_sh[2], red_sh[3]));
    __syncthreads();
    float s = 0.0f;
    for (int t = tid; t < TT; t += 256) {
        const float e = __expf(logit_sh[t] - m);
        logit_sh[t] = e;
        s += e;
    }
    #pragma unroll
    for (int off = 32; off > 0; off >>= 1) s += __shfl_xor(s, off, 64);
    if (lane == 0) red_sh[wave] = s;
    __syncthreads();
    s = red_sh[0] + red_sh[1] + red_sh[2] + red_sh[3];
    const float inv_s = 1.0f / s;

    // phase 3: ctx = sum_t softmax[t] * out2[b,t,:]
    float acc = 0.0f;
    for (int t = wave; t < TT; t += 4)
        acc += logit_sh[t] * out2[((size_t)b*TT + t)*64 + lane];
    ctx_sh[wave][lane] = acc;
    __syncthreads();
    if (wave == 0) {
        const float c = (ctx_sh[0][lane] + ctx_sh[1][lane] +
                         ctx_sh[2][lane] + ctx_sh[3][lane]) * inv_s;
        float v = c * fc_w[lane];
        #pragma unroll
        for (int off = 32; off > 0; off >>= 1) v += __shfl_xor(v, off, 64);
        if (lane == 0) out[b] = sigmoidf_(v + fc_b[0]);
    }
}

extern "C" void kernel_launch(void* const* d_in, const int* in_sizes, int n_in,
                              void* d_out, int out_size, void* d_ws, size_t ws_size,
                              hipStream_t stream) {
    (void)in_sizes; (void)n_in; (void)out_size; (void)ws_size;
    const float* x      = (const float*)d_in[0];
    const float* w_ih0  = (const float*)d_in[1];
    const float* w_hh0  = (const float*)d_in[2];
    const float* b_ih0  = (const float*)d_in[3];
    const float* b_hh0  = (const float*)d_in[4];
    const float* w_ih1  = (const float*)d_in[5];
    const float* w_hh1  = (const float*)d_in[6];
    const float* b_ih1  = (const float*)d_in[7];
    const float* b_hh1  = (const float*)d_in[8];
    const float* attn_w = (const float*)d_in[9];
    const float* attn_b = (const float*)d_in[10];
    const float* fc_w   = (const float*)d_in[11];
    const float* fc_b   = (const float*)d_in[12];
    float* out = (float*)d_out;

    float* h1   = (float*)d_ws;                       // 128 MiB
    float* out2 = h1 + (size_t)BB * TT * 64;          // 128 MiB

    gru_l0<<<BB, 192, 0, stream>>>(x, w_ih0, w_hh0, b_ih0, b_hh0, h1);
    gru_l1<<<BB, 192, 0, stream>>>(h1, w_ih1, w_hh1, b_ih1, b_hh1, out2);
    attn_fc<<<BB, 256, 0, stream>>>(out2, attn_w, attn_b, fc_w, fc_b, out);
}

// Round 2
// 1086.081 us; speedup vs baseline: 1.0618x; 1.0618x over previous
//
#include <hip/hip_runtime.h>
#include <math.h>

#define BB 1024
#define TT 512

__device__ __forceinline__ float fast_rcp(float x){ return __builtin_amdgcn_rcpf(x); }
__device__ __forceinline__ float sigmoidf_(float x){ return fast_rcp(1.0f + __expf(-x)); }
__device__ __forceinline__ float tanhf_(float x){
    float t = __expf(2.0f * x);
    return 1.0f - 2.0f * fast_rcp(t + 1.0f);
}

// Layer 0 bidirectional GRU. Block = 1 wave (64) = one batch element.
// Lane layout: d = lane>>5 (direction), i = lane&31 (h element).
// Each lane computes gates r_i, z_i, n_i and h_i fully in-lane.
// No __syncthreads: single-wave block, LDS ordering via in-wave lgkmcnt.
__global__ __launch_bounds__(64, 1) void gru_l0(
    const float* __restrict__ x,      // (B,T,4)
    const float* __restrict__ w_ih,   // (2,96,4)
    const float* __restrict__ w_hh,   // (2,96,32)
    const float* __restrict__ b_ih,   // (2,96)
    const float* __restrict__ b_hh,   // (2,96)
    float* __restrict__ h1)           // (B,T,64)
{
    const int b    = blockIdx.x;
    const int lane = threadIdx.x;
    const int d    = lane >> 5;
    const int i    = lane & 31;

    float4 wi[3]; float4 wh[3][8]; float bi[3], bh[3];
    #pragma unroll
    for (int g = 0; g < 3; ++g) {
        const int row = d*96 + g*32 + i;
        wi[g] = *(const float4*)(w_ih + (size_t)row*4);
        #pragma unroll
        for (int k = 0; k < 8; ++k)
            wh[g][k] = *(const float4*)(w_hh + (size_t)row*32 + k*4);
        bi[g] = b_ih[d*96 + g*32 + i];
        bh[g] = b_hh[d*96 + g*32 + i];
    }

    __shared__ __align__(16) float h_sh[2][32];
    h_sh[d][i] = 0.0f;
    float h = 0.0f;

    const size_t xbase = (size_t)b * TT;
    float4 xc = *(const float4*)(x + (xbase + (d ? TT-1 : 0))*4);

    for (int t = 0; t < TT; ++t) {
        const int tx = d ? (TT-1-t) : t;
        // prefetch next input row (register, 1 step ahead)
        float4 xn4 = xc;
        if (t+1 < TT) {
            const int tx1 = d ? (TT-2-t) : (t+1);
            xn4 = *(const float4*)(x + (xbase + tx1)*4);
        }
        float xg[3], hg[3];
        #pragma unroll
        for (int g = 0; g < 3; ++g) {
            xg[g] = bi[g] + xc.x*wi[g].x + xc.y*wi[g].y + xc.z*wi[g].z + xc.w*wi[g].w;
            hg[g] = bh[g];
        }
        #pragma unroll
        for (int k = 0; k < 8; ++k) {
            const float4 hv = *(const float4*)&h_sh[d][k*4];   // 2-way broadcast, free
            #pragma unroll
            for (int g = 0; g < 3; ++g)
                hg[g] += hv.x*wh[g][k].x + hv.y*wh[g][k].y + hv.z*wh[g][k].z + hv.w*wh[g][k].w;
        }
        const float r = sigmoidf_(xg[0] + hg[0]);
        const float z = sigmoidf_(xg[1] + hg[1]);
        const float n = tanhf_(xg[2] + r*hg[2]);
        h = (1.0f - z)*n + z*h;
        h_sh[d][i] = h;
        h1[(xbase + tx)*64 + d*32 + i] = h;
        xc = xn4;
    }
}

// Layer 1 bidirectional GRU, input width 64, projection fused, weights in VGPRs
// (~340). Input rows double-buffered in LDS with 2-step-ahead global prefetch.
__global__ __launch_bounds__(64, 1) void gru_l1(
    const float* __restrict__ h1,     // (B,T,64)
    const float* __restrict__ w_ih,   // (2,96,64)
    const float* __restrict__ w_hh,   // (2,96,32)
    const float* __restrict__ b_ih,   // (2,96)
    const float* __restrict__ b_hh,   // (2,96)
    float* __restrict__ out2)         // (B,T,64)
{
    const int b    = blockIdx.x;
    const int lane = threadIdx.x;
    const int d    = lane >> 5;
    const int i    = lane & 31;

    float4 wi[3][16]; float4 wh[3][8]; float bi[3], bh[3];
    #pragma unroll
    for (int g = 0; g < 3; ++g) {
        const size_t row = (size_t)(d*96 + g*32 + i);
        #pragma unroll
        for (int k = 0; k < 16; ++k)
            wi[g][k] = *(const float4*)(w_ih + row*64 + k*4);
        #pragma unroll
        for (int k = 0; k < 8; ++k)
            wh[g][k] = *(const float4*)(w_hh + row*32 + k*4);
        bi[g] = b_ih[d*96 + g*32 + i];
        bh[g] = b_hh[d*96 + g*32 + i];
    }

    __shared__ __align__(16) float h_sh[2][32];
    __shared__ __align__(16) float xbuf[2][2][64];   // [buf][dir][64]
    h_sh[d][i] = 0.0f;
    float h = 0.0f;

    const size_t base = (size_t)b * TT;
    const int li = (lane & 31) * 2;   // this lane's 2 floats of its dir's row

    float2 c1;
    {
        const int r0 = d ? (TT-1) : 0;
        const float2 c0 = *(const float2*)(h1 + (base + r0)*64 + li);
        *(float2*)&xbuf[0][d][li] = c0;
        const int r1 = d ? (TT-2) : 1;
        c1 = *(const float2*)(h1 + (base + r1)*64 + li);
    }

    int buf = 0;
    for (int t = 0; t < TT; ++t) {
        // issue prefetch for row t+2 first (covers ~2 steps of latency)
        float2 c2 = c1;
        if (t+2 < TT) {
            const int r2 = d ? (TT-3-t) : (t+2);
            c2 = *(const float2*)(h1 + (base + r2)*64 + li);
        }
        float xg[3], hg[3];
        #pragma unroll
        for (int g = 0; g < 3; ++g) { xg[g] = bi[g]; hg[g] = bh[g]; }
        #pragma unroll
        for (int k = 0; k < 16; ++k) {
            const float4 xv = *(const float4*)&xbuf[buf][d][k*4];  // broadcast, free
            #pragma unroll
            for (int g = 0; g < 3; ++g)
                xg[g] += xv.x*wi[g][k].x + xv.y*wi[g][k].y + xv.z*wi[g][k].z + xv.w*wi[g][k].w;
        }
        #pragma unroll
        for (int k = 0; k < 8; ++k) {
            const float4 hv = *(const float4*)&h_sh[d][k*4];       // broadcast, free
            #pragma unroll
            for (int g = 0; g < 3; ++g)
                hg[g] += hv.x*wh[g][k].x + hv.y*wh[g][k].y + hv.z*wh[g][k].z + hv.w*wh[g][k].w;
        }
        const float r = sigmoidf_(xg[0] + hg[0]);
        const float z = sigmoidf_(xg[1] + hg[1]);
        const float n = tanhf_(xg[2] + r*hg[2]);
        h = (1.0f - z)*n + z*h;
        h_sh[d][i] = h;
        const int tx = d ? (TT-1-t) : t;
        out2[(base + tx)*64 + d*32 + i] = h;
        if (t+1 < TT) *(float2*)&xbuf[buf^1][d][li] = c1;  // compiler waits vmcnt here
        c1 = c2;
        buf ^= 1;
    }
}

// Attention pooling + FC + sigmoid. One block per batch element.
__global__ __launch_bounds__(256) void attn_fc(
    const float* __restrict__ out2,   // (B,T,64)
    const float* __restrict__ attn_w, // (64)
    const float* __restrict__ attn_b, // (1)
    const float* __restrict__ fc_w,   // (64)
    const float* __restrict__ fc_b,   // (1)
    float* __restrict__ out)          // (B,1)
{
    const int b    = blockIdx.x;
    const int tid  = threadIdx.x;
    const int wave = tid >> 6;
    const int lane = tid & 63;

    __shared__ float logit_sh[TT];
    __shared__ float red_sh[4];
    __shared__ float ctx_sh[4][64];

    const float aw = attn_w[lane];
    const float ab = attn_b[0];

    for (int t = wave; t < TT; t += 4) {
        float v = out2[((size_t)b*TT + t)*64 + lane] * aw;
        #pragma unroll
        for (int off = 32; off > 0; off >>= 1) v += __shfl_xor(v, off, 64);
        if (lane == 0) logit_sh[t] = v + ab;
    }
    __syncthreads();

    float m = -INFINITY;
    for (int t = tid; t < TT; t += 256) m = fmaxf(m, logit_sh[t]);
    #pragma unroll
    for (int off = 32; off > 0; off >>= 1) m = fmaxf(m, __shfl_xor(m, off, 64));
    if (lane == 0) red_sh[wave] = m;
    __syncthreads();
    m = fmaxf(fmaxf(red_sh[0], red_sh[1]), fmaxf(red_sh[2], red_sh[3]));
    __syncthreads();
    float s = 0.0f;
    for (int t = tid; t < TT; t += 256) {
        const float e = __expf(logit_sh[t] - m);
        logit_sh[t] = e;
        s += e;
    }
    #pragma unroll
    for (int off = 32; off > 0; off >>= 1) s += __shfl_xor(s, off, 64);
    if (lane == 0) red_sh[wave] = s;
    __syncthreads();
    s = red_sh[0] + red_sh[1] + red_sh[2] + red_sh[3];
    const float inv_s = 1.0f / s;

    float acc = 0.0f;
    for (int t = wave; t < TT; t += 4)
        acc += logit_sh[t] * out2[((size_t)b*TT + t)*64 + lane];
    ctx_sh[wave][lane] = acc;
    __syncthreads();
    if (wave == 0) {
        const float c = (ctx_sh[0][lane] + ctx_sh[1][lane] +
                         ctx_sh[2][lane] + ctx_sh[3][lane]) * inv_s;
        float v = c * fc_w[lane];
        #pragma unroll
        for (int off = 32; off > 0; off >>= 1) v += __shfl_xor(v, off, 64);
        if (lane == 0) out[b] = sigmoidf_(v + fc_b[0]);
    }
}

extern "C" void kernel_launch(void* const* d_in, const int* in_sizes, int n_in,
                              void* d_out, int out_size, void* d_ws, size_t ws_size,
                              hipStream_t stream) {
    (void)in_sizes; (void)n_in; (void)out_size; (void)ws_size;
    const float* x      = (const float*)d_in[0];
    const float* w_ih0  = (const float*)d_in[1];
    const float* w_hh0  = (const float*)d_in[2];
    const float* b_ih0  = (const float*)d_in[3];
    const float* b_hh0  = (const float*)d_in[4];
    const float* w_ih1  = (const float*)d_in[5];
    const float* w_hh1  = (const float*)d_in[6];
    const float* b_ih1  = (const float*)d_in[7];
    const float* b_hh1  = (const float*)d_in[8];
    const float* attn_w = (const float*)d_in[9];
    const float* attn_b = (const float*)d_in[10];
    const float* fc_w   = (const float*)d_in[11];
    const float* fc_b   = (const float*)d_in[12];
    float* out = (float*)d_out;

    float* h1   = (float*)d_ws;                       // 128 MiB
    float* out2 = h1 + (size_t)BB * TT * 64;          // 128 MiB

    gru_l0<<<BB, 64, 0, stream>>>(x, w_ih0, w_hh0, b_ih0, b_hh0, h1);
    gru_l1<<<BB, 64, 0, stream>>>(h1, w_ih1, w_hh1, b_ih1, b_hh1, out2);
    attn_fc<<<BB, 256, 0, stream>>>(out2, attn_w, attn_b, fc_w, fc_b, out);
}

// Round 4
// 890.882 us; speedup vs baseline: 1.2945x; 1.2191x over previous
//
#include <hip/hip_runtime.h>
#include <math.h>

#define BB 1024
#define TT 512

__device__ __forceinline__ float fast_rcp(float x){ return __builtin_amdgcn_rcpf(x); }
__device__ __forceinline__ float sigmoidf_(float x){ return fast_rcp(1.0f + __expf(-x)); }
__device__ __forceinline__ float tanhf_(float x){
    float t = __expf(2.0f * x);
    return 1.0f - 2.0f * fast_rcp(t + 1.0f);
}

// Layer 0 bidirectional GRU. Block = 1 wave = one (batch, direction) sequence.
// lane = i + 32*half: i = h-element, half = k-split half of the recurrent dot.
// Bias handling: r,z gates fold b_ih+b_hh into xg; n gate keeps b_hh_n
// separate — it must be multiplied by r (reference: n = tanh(xn + r*(h·W+b_hh_n))).
__global__ __launch_bounds__(64, 2) void gru_l0(
    const float* __restrict__ x,      // (B,T,4)
    const float* __restrict__ w_ih,   // (2,96,4)
    const float* __restrict__ w_hh,   // (2,96,32)
    const float* __restrict__ b_ih,   // (2,96)
    const float* __restrict__ b_hh,   // (2,96)
    float* __restrict__ h1)           // (B,T,64)
{
    const int b    = blockIdx.x >> 1;
    const int d    = blockIdx.x & 1;
    const int lane = threadIdx.x;
    const int i    = lane & 31;
    const int half = lane >> 5;

    float4 wi[3];        // full input row (4), redundant across halves
    float4 wh[3][4];     // recurrent row, j-range [half*16, half*16+16)
    float  bx[3];        // g=0,1: b_ih+b_hh ; g=2: b_ih only
    float  bhn;          // b_hh for n gate (stays inside r*(...))
    #pragma unroll
    for (int g = 0; g < 3; ++g) {
        const int row = d*96 + g*32 + i;
        wi[g] = *(const float4*)(w_ih + (size_t)row*4);
        #pragma unroll
        for (int k = 0; k < 4; ++k)
            wh[g][k] = *(const float4*)(w_hh + (size_t)row*32 + half*16 + k*4);
        bx[g] = (g < 2) ? (b_ih[row] + b_hh[row]) : b_ih[row];
    }
    bhn = b_hh[d*96 + 2*32 + i];

    __shared__ __align__(16) float h_sh[32];
    if (!half) h_sh[i] = 0.0f;
    float h = 0.0f;

    const size_t xbase = (size_t)b * TT;
    float4 xc = *(const float4*)(x + (xbase + (d ? TT-1 : 0))*4);

    for (int t = 0; t < TT; ++t) {
        const int tx = d ? (TT-1-t) : t;
        float4 xn4 = xc;
        if (t+1 < TT) {
            const int tx1 = d ? (TT-2-t) : (t+1);
            xn4 = *(const float4*)(x + (xbase + tx1)*4);
        }
        float xg[3], hg[3];
        #pragma unroll
        for (int g = 0; g < 3; ++g) {
            xg[g] = bx[g] + xc.x*wi[g].x + xc.y*wi[g].y + xc.z*wi[g].z + xc.w*wi[g].w;
            hg[g] = 0.0f;
        }
        #pragma unroll
        for (int k = 0; k < 4; ++k) {
            const float4 hv = *(const float4*)&h_sh[half*16 + k*4];  // per-half broadcast
            #pragma unroll
            for (int g = 0; g < 3; ++g)
                hg[g] += hv.x*wh[g][k].x + hv.y*wh[g][k].y + hv.z*wh[g][k].z + hv.w*wh[g][k].w;
        }
        #pragma unroll
        for (int g = 0; g < 3; ++g) hg[g] += __shfl_xor(hg[g], 32, 64);
        const float r = sigmoidf_(xg[0] + hg[0]);
        const float z = sigmoidf_(xg[1] + hg[1]);
        const float n = tanhf_(xg[2] + r*(hg[2] + bhn));
        h = n + z*(h - n);
        if (!half) {
            h_sh[i] = h;
            h1[(xbase + tx)*64 + d*32 + i] = h;
        }
        xc = xn4;
    }
}

// Layer 1 bidirectional GRU, input width 64. Same wave layout; projection
// k-split too (wi: 96 VGPR, wh: 48 VGPR -> ~180 total, no spill).
// Input rows double-buffered through LDS with 2-step-ahead global prefetch.
__global__ __launch_bounds__(64, 2) void gru_l1(
    const float* __restrict__ h1,     // (B,T,64)
    const float* __restrict__ w_ih,   // (2,96,64)
    const float* __restrict__ w_hh,   // (2,96,32)
    const float* __restrict__ b_ih,   // (2,96)
    const float* __restrict__ b_hh,   // (2,96)
    float* __restrict__ out2)         // (B,T,64)
{
    const int b    = blockIdx.x >> 1;
    const int d    = blockIdx.x & 1;
    const int lane = threadIdx.x;
    const int i    = lane & 31;
    const int half = lane >> 5;

    float4 wi[3][8];     // proj row, k-range [half*32, half*32+32)
    float4 wh[3][4];     // rec row, j-range [half*16, half*16+16)
    float  bx[3];
    float  bhn;
    #pragma unroll
    for (int g = 0; g < 3; ++g) {
        const size_t row = (size_t)(d*96 + g*32 + i);
        #pragma unroll
        for (int k = 0; k < 8; ++k)
            wi[g][k] = *(const float4*)(w_ih + row*64 + half*32 + k*4);
        #pragma unroll
        for (int k = 0; k < 4; ++k)
            wh[g][k] = *(const float4*)(w_hh + row*32 + half*16 + k*4);
        bx[g] = (g < 2) ? (b_ih[row] + b_hh[row]) : b_ih[row];
    }
    bhn = b_hh[d*96 + 2*32 + i];

    __shared__ __align__(16) float h_sh[32];
    __shared__ __align__(16) float xbuf[2][64];
    if (!half) h_sh[i] = 0.0f;
    float h = 0.0f;

    const size_t base = (size_t)b * TT;

    // stage row 0; prefetch row 1 (1 float per lane, coalesced 256B)
    float c1;
    {
        const int r0 = d ? (TT-1) : 0;
        xbuf[0][lane] = h1[(base + r0)*64 + lane];
        const int r1 = d ? (TT-2) : 1;
        c1 = h1[(base + r1)*64 + lane];
    }

    int buf = 0;
    for (int t = 0; t < TT; ++t) {
        // prefetch row t+2 (2 steps of latency cover)
        float c2 = c1;
        if (t+2 < TT) {
            const int r2 = d ? (TT-3-t) : (t+2);
            c2 = h1[(base + r2)*64 + lane];
        }
        // projection from staged row (independent of h -> hides h LDS round trip)
        float xg[3], hg[3];
        #pragma unroll
        for (int g = 0; g < 3; ++g) { xg[g] = bx[g]; hg[g] = 0.0f; }
        #pragma unroll
        for (int k = 0; k < 8; ++k) {
            const float4 xv = *(const float4*)&xbuf[buf][half*32 + k*4];  // broadcast
            #pragma unroll
            for (int g = 0; g < 3; ++g)
                xg[g] += xv.x*wi[g][k].x + xv.y*wi[g][k].y + xv.z*wi[g][k].z + xv.w*wi[g][k].w;
        }
        // stage row t+1 into the other buffer (c1 ready from last iter's prefetch)
        if (t+1 < TT) xbuf[buf^1][lane] = c1;
        // recurrent part
        #pragma unroll
        for (int k = 0; k < 4; ++k) {
            const float4 hv = *(const float4*)&h_sh[half*16 + k*4];       // broadcast
            #pragma unroll
            for (int g = 0; g < 3; ++g)
                hg[g] += hv.x*wh[g][k].x + hv.y*wh[g][k].y + hv.z*wh[g][k].z + hv.w*wh[g][k].w;
        }
        #pragma unroll
        for (int g = 0; g < 3; ++g) hg[g] += __shfl_xor(hg[g], 32, 64);
        const float r = sigmoidf_(xg[0] + hg[0]);
        const float z = sigmoidf_(xg[1] + hg[1]);
        const float n = tanhf_(xg[2] + r*(hg[2] + bhn));
        h = n + z*(h - n);
        if (!half) {
            h_sh[i] = h;
            const int tx = d ? (TT-1-t) : t;
            out2[(base + tx)*64 + d*32 + i] = h;
        }
        c1 = c2;
        buf ^= 1;
    }
}

// Attention pooling + FC + sigmoid. One block per batch element.
__global__ __launch_bounds__(256) void attn_fc(
    const float* __restrict__ out2,   // (B,T,64)
    const float* __restrict__ attn_w, // (64)
    const float* __restrict__ attn_b, // (1)
    const float* __restrict__ fc_w,   // (64)
    const float* __restrict__ fc_b,   // (1)
    float* __restrict__ out)          // (B,1)
{
    const int b    = blockIdx.x;
    const int tid  = threadIdx.x;
    const int wave = tid >> 6;
    const int lane = tid & 63;

    __shared__ float logit_sh[TT];
    __shared__ float red_sh[4];
    __shared__ float ctx_sh[4][64];

    const float aw = attn_w[lane];
    const float ab = attn_b[0];

    for (int t = wave; t < TT; t += 4) {
        float v = out2[((size_t)b*TT + t)*64 + lane] * aw;
        #pragma unroll
        for (int off = 32; off > 0; off >>= 1) v += __shfl_xor(v, off, 64);
        if (lane == 0) logit_sh[t] = v + ab;
    }
    __syncthreads();

    float m = -INFINITY;
    for (int t = tid; t < TT; t += 256) m = fmaxf(m, logit_sh[t]);
    #pragma unroll
    for (int off = 32; off > 0; off >>= 1) m = fmaxf(m, __shfl_xor(m, off, 64));
    if (lane == 0) red_sh[wave] = m;
    __syncthreads();
    m = fmaxf(fmaxf(red_sh[0], red_sh[1]), fmaxf(red_sh[2], red_sh[3]));
    __syncthreads();
    float s = 0.0f;
    for (int t = tid; t < TT; t += 256) {
        const float e = __expf(logit_sh[t] - m);
        logit_sh[t] = e;
        s += e;
    }
    #pragma unroll
    for (int off = 32; off > 0; off >>= 1) s += __shfl_xor(s, off, 64);
    if (lane == 0) red_sh[wave] = s;
    __syncthreads();
    s = red_sh[0] + red_sh[1] + red_sh[2] + red_sh[3];
    const float inv_s = 1.0f / s;

    float acc = 0.0f;
    for (int t = wave; t < TT; t += 4)
        acc += logit_sh[t] * out2[((size_t)b*TT + t)*64 + lane];
    ctx_sh[wave][lane] = acc;
    __syncthreads();
    if (wave == 0) {
        const float c = (ctx_sh[0][lane] + ctx_sh[1][lane] +
                         ctx_sh[2][lane] + ctx_sh[3][lane]) * inv_s;
        float v = c * fc_w[lane];
        #pragma unroll
        for (int off = 32; off > 0; off >>= 1) v += __shfl_xor(v, off, 64);
        if (lane == 0) out[b] = sigmoidf_(v + fc_b[0]);
    }
}

extern "C" void kernel_launch(void* const* d_in, const int* in_sizes, int n_in,
                              void* d_out, int out_size, void* d_ws, size_t ws_size,
                              hipStream_t stream) {
    (void)in_sizes; (void)n_in; (void)out_size; (void)ws_size;
    const float* x      = (const float*)d_in[0];
    const float* w_ih0  = (const float*)d_in[1];
    const float* w_hh0  = (const float*)d_in[2];
    const float* b_ih0  = (const float*)d_in[3];
    const float* b_hh0  = (const float*)d_in[4];
    const float* w_ih1  = (const float*)d_in[5];
    const float* w_hh1  = (const float*)d_in[6];
    const float* b_ih1  = (const float*)d_in[7];
    const float* b_hh1  = (const float*)d_in[8];
    const float* attn_w = (const float*)d_in[9];
    const float* attn_b = (const float*)d_in[10];
    const float* fc_w   = (const float*)d_in[11];
    const float* fc_b   = (const float*)d_in[12];
    float* out = (float*)d_out;

    float* h1   = (float*)d_ws;                       // 128 MiB
    float* out2 = h1 + (size_t)BB * TT * 64;          // 128 MiB

    gru_l0<<<BB*2, 64, 0, stream>>>(x, w_ih0, w_hh0, b_ih0, b_hh0, h1);
    gru_l1<<<BB*2, 64, 0, stream>>>(h1, w_ih1, w_hh1, b_ih1, b_hh1, out2);
    attn_fc<<<BB, 256, 0, stream>>>(out2, attn_w, attn_b, fc_w, fc_b, out);
}